// Round 1
// baseline (122.541 us; speedup 1.0000x reference)
//
#include <hip/hip_runtime.h>
#include <math.h>

#define N_RAYS 65536
#define T_SAMPLES 128
#define HID 16

__global__ __launch_bounds__(256) void radiance_kernel(
    const float* __restrict__ o,
    const float* __restrict__ d,
    const float* __restrict__ tnear,
    const float* __restrict__ tfar,
    const float* __restrict__ noise,
    const float* __restrict__ W1,
    const float* __restrict__ b1,
    const float* __restrict__ w_sigma,
    const float* __restrict__ W_rgb,
    float* __restrict__ out)
{
    const int ray = blockIdx.x * blockDim.x + threadIdx.x;
    if (ray >= N_RAYS) return;

    const float ox = o[ray*3+0], oy = o[ray*3+1], oz = o[ray*3+2];
    const float dx = d[ray*3+0], dy = d[ray*3+1], dz = d[ray*3+2];
    const float tn = tnear[ray];
    const float tf = tfar[ray];
    const float dnorm = sqrtf(dx*dx + dy*dy + dz*dz);
    const float range = tf - tn;
    const float invT = 1.0f / (float)T_SAMPLES;

    // Hoisted MLP layer 1: h_j(ts) = relu(A_j + ts*B_j)
    float A[HID], B[HID];
#pragma unroll
    for (int j = 0; j < HID; ++j) {
        const float w0 = W1[0*HID + j], w1 = W1[1*HID + j], w2 = W1[2*HID + j];
        A[j] = fmaf(ox, w0, fmaf(oy, w1, fmaf(oz, w2, b1[j])));
        B[j] = fmaf(dx, w0, fmaf(dy, w1, dz * w2));
    }
    // Output weights in registers (broadcast loads, L1/L2 served)
    float WS[HID], WR[HID], WG[HID], WB[HID];
#pragma unroll
    for (int j = 0; j < HID; ++j) {
        WS[j] = w_sigma[j];
        WR[j] = W_rgb[j*3+0];
        WG[j] = W_rgb[j*3+1];
        WB[j] = W_rgb[j*3+2];
    }

    float trans = 1.0f;
    float cr = 0.f, cg = 0.f, cb = 0.f, cd = 0.f, ca = 0.f;
    float p_ts = 0.f, p_sig = 0.f, p_r = 0.f, p_g = 0.f, p_b = 0.f;

    float nz = noise[ray];  // noise for t = 0
    for (int t = 0; t < T_SAMPLES; ++t) {
        const float ts = fmaf(range, ((float)t + nz) * invT, tn);
        // prefetch next iteration's noise before the heavy compute
        if (t + 1 < T_SAMPLES) nz = noise[(size_t)(t+1)*N_RAYS + ray];

        float sp = 0.f, rr = 0.f, gg = 0.f, bb = 0.f;
#pragma unroll
        for (int j = 0; j < HID; ++j) {
            const float h = fmaxf(fmaf(ts, B[j], A[j]), 0.0f);
            sp = fmaf(h, WS[j], sp);
            rr = fmaf(h, WR[j], rr);
            gg = fmaf(h, WG[j], gg);
            bb = fmaf(h, WB[j], bb);
        }
        // softplus (stable): max(x,0) + log1p(exp(-|x|))
        const float e = __expf(-fabsf(sp));
        const float sigma = fmaxf(sp, 0.0f) + __logf(1.0f + e);
        // sigmoids
        const float r = __builtin_amdgcn_rcpf(1.0f + __expf(-rr));
        const float g = __builtin_amdgcn_rcpf(1.0f + __expf(-gg));
        const float b = __builtin_amdgcn_rcpf(1.0f + __expf(-bb));

        if (t > 0) {
            const float delta = ts - p_ts;
            const float sd = p_sig * delta * dnorm;
            const float et = __expf(-sd);
            const float w = trans * (1.0f - et);
            cr = fmaf(w, p_r, cr);
            cg = fmaf(w, p_g, cg);
            cb = fmaf(w, p_b, cb);
            cd = fmaf(w, p_ts, cd);
            ca += w;
            trans *= et;
        }
        p_ts = ts; p_sig = sigma; p_r = r; p_g = g; p_b = b;
    }
    // last sample: delta = tfar - ts[T-1]
    {
        const float delta = tf - p_ts;
        const float sd = p_sig * delta * dnorm;
        const float et = __expf(-sd);
        const float w = trans * (1.0f - et);
        cr = fmaf(w, p_r, cr);
        cg = fmaf(w, p_g, cg);
        cb = fmaf(w, p_b, cb);
        cd = fmaf(w, p_ts, cd);
        ca += w;
    }

    out[ray*5+0] = cr;
    out[ray*5+1] = cg;
    out[ray*5+2] = cb;
    out[ray*5+3] = cd;
    out[ray*5+4] = ca;
}

extern "C" void kernel_launch(void* const* d_in, const int* in_sizes, int n_in,
                              void* d_out, int out_size, void* d_ws, size_t ws_size,
                              hipStream_t stream) {
    const float* o       = (const float*)d_in[0];
    const float* d       = (const float*)d_in[1];
    const float* tnear   = (const float*)d_in[2];
    const float* tfar    = (const float*)d_in[3];
    const float* noise   = (const float*)d_in[4];
    const float* W1      = (const float*)d_in[5];
    const float* b1      = (const float*)d_in[6];
    const float* w_sigma = (const float*)d_in[7];
    const float* W_rgb   = (const float*)d_in[8];
    float* out = (float*)d_out;

    dim3 block(256);
    dim3 grid((N_RAYS + 255) / 256);
    hipLaunchKernelGGL(radiance_kernel, grid, block, 0, stream,
                       o, d, tnear, tfar, noise, W1, b1, w_sigma, W_rgb, out);
}

// Round 2
// 119.914 us; speedup vs baseline: 1.0219x; 1.0219x over previous
//
#include <hip/hip_runtime.h>
#include <math.h>

#define N_RAYS 65536
#define T_SAMPLES 128
#define HID 16

#define RAYS_PER_BLOCK 64
#define CHUNKS 4
#define CHUNK_LEN (T_SAMPLES / CHUNKS)   // 32

// log2(e)
#define L2E 1.4426950408889634f

__global__ __launch_bounds__(256) void radiance_kernel(
    const float* __restrict__ o,
    const float* __restrict__ d,
    const float* __restrict__ tnear,
    const float* __restrict__ tfar,
    const float* __restrict__ noise,
    const float* __restrict__ W1,
    const float* __restrict__ b1,
    const float* __restrict__ w_sigma,
    const float* __restrict__ W_rgb,
    float* __restrict__ out)
{
    const int lane  = threadIdx.x & 63;   // ray within block (wave-coherent)
    const int chunk = threadIdx.x >> 6;   // 0..3 (one wave per chunk)
    const int ray   = blockIdx.x * RAYS_PER_BLOCK + lane;

    // ---- per-ray setup (duplicated across the 4 chunk-waves; cheap) ----
    const float ox = o[ray*3+0], oy = o[ray*3+1], oz = o[ray*3+2];
    const float dx = d[ray*3+0], dy = d[ray*3+1], dz = d[ray*3+2];
    const float tn = tnear[ray];
    const float tf = tfar[ray];
    const float dnorm = sqrtf(dx*dx + dy*dy + dz*dz);
    const float range = tf - tn;
    const float invT = 1.0f / (float)T_SAMPLES;

    // Hoisted MLP layer 1: h_j(ts) = relu(A_j + ts*B_j)
    float A[HID], B[HID];
#pragma unroll
    for (int j = 0; j < HID; ++j) {
        const float w0 = W1[0*HID + j], w1 = W1[1*HID + j], w2 = W1[2*HID + j];
        A[j] = fmaf(ox, w0, fmaf(oy, w1, fmaf(oz, w2, b1[j])));
        B[j] = fmaf(dx, w0, fmaf(dy, w1, dz * w2));
    }
    // Output weights: uniform-indexed -> compiler promotes to SGPRs
    float WS[HID], WR[HID], WG[HID], WB[HID];
#pragma unroll
    for (int j = 0; j < HID; ++j) {
        WS[j] = w_sigma[j];
        WR[j] = W_rgb[j*3+0];
        WG[j] = W_rgb[j*3+1];
        WB[j] = W_rgb[j*3+2];
    }

    // ---- this thread's sample chunk [t0, t0+CHUNK_LEN) ----
    const int t0 = chunk * CHUNK_LEN;
    float nz = noise[(size_t)t0 * N_RAYS + ray];
    float ts = fmaf(range, ((float)t0 + nz) * invT, tn);

    float lt = 1.0f;   // local transmittance within chunk
    float cr = 0.f, cg = 0.f, cb = 0.f, cd = 0.f, ca = 0.f;

    for (int i = 0; i < CHUNK_LEN; ++i) {
        const int t = t0 + i;
        // next sample position (crosses chunk boundary via one extra noise read)
        float ts_next;
        if (t + 1 < T_SAMPLES) {
            const float nz2 = noise[(size_t)(t+1) * N_RAYS + ray];
            ts_next = fmaf(range, ((float)(t+1) + nz2) * invT, tn);
        } else {
            ts_next = tf;
        }

        float sp = 0.f, rr = 0.f, gg = 0.f, bb = 0.f;
#pragma unroll
        for (int j = 0; j < HID; ++j) {
            const float h = fmaxf(fmaf(ts, B[j], A[j]), 0.0f);
            sp = fmaf(h, WS[j], sp);
            rr = fmaf(h, WR[j], rr);
            gg = fmaf(h, WG[j], gg);
            bb = fmaf(h, WB[j], bb);
        }

        // l2 = log2(1 + exp(sp))  (stable):  max(sp,0)*L2E + log2(1 + exp2(-|sp|*L2E))
        const float e  = __builtin_amdgcn_exp2f(-fabsf(sp) * L2E);
        const float l2 = fmaf(fmaxf(sp, 0.0f), L2E, __builtin_amdgcn_logf(1.0f + e));
        // exp(-sigma*delta*dnorm) = 2^(-delta*dnorm*l2)
        const float dd = (ts_next - ts) * dnorm;
        const float et = __builtin_amdgcn_exp2f(-dd * l2);

        // sigmoids via base-2
        const float r = __builtin_amdgcn_rcpf(1.0f + __builtin_amdgcn_exp2f(-rr * L2E));
        const float g = __builtin_amdgcn_rcpf(1.0f + __builtin_amdgcn_exp2f(-gg * L2E));
        const float b = __builtin_amdgcn_rcpf(1.0f + __builtin_amdgcn_exp2f(-bb * L2E));

        const float w = lt * (1.0f - et);
        cr = fmaf(w, r, cr);
        cg = fmaf(w, g, cg);
        cb = fmaf(w, b, cb);
        cd = fmaf(w, ts, cd);
        ca += w;
        lt *= et;
        ts = ts_next;
    }

    // ---- combine chunks: out_c scaled by product of previous chunks' lt ----
    __shared__ float s_lt[CHUNKS][RAYS_PER_BLOCK];
    __shared__ float s_acc[CHUNKS][5][RAYS_PER_BLOCK];
    s_lt[chunk][lane] = lt;
    s_acc[chunk][0][lane] = cr;
    s_acc[chunk][1][lane] = cg;
    s_acc[chunk][2][lane] = cb;
    s_acc[chunk][3][lane] = cd;
    s_acc[chunk][4][lane] = ca;
    __syncthreads();

    if (chunk == 0) {
        float scale = 1.0f;
        float a0 = 0.f, a1 = 0.f, a2 = 0.f, a3 = 0.f, a4 = 0.f;
#pragma unroll
        for (int c = 0; c < CHUNKS; ++c) {
            a0 = fmaf(scale, s_acc[c][0][lane], a0);
            a1 = fmaf(scale, s_acc[c][1][lane], a1);
            a2 = fmaf(scale, s_acc[c][2][lane], a2);
            a3 = fmaf(scale, s_acc[c][3][lane], a3);
            a4 = fmaf(scale, s_acc[c][4][lane], a4);
            scale *= s_lt[c][lane];
        }
        out[ray*5+0] = a0;
        out[ray*5+1] = a1;
        out[ray*5+2] = a2;
        out[ray*5+3] = a3;
        out[ray*5+4] = a4;
    }
}

extern "C" void kernel_launch(void* const* d_in, const int* in_sizes, int n_in,
                              void* d_out, int out_size, void* d_ws, size_t ws_size,
                              hipStream_t stream) {
    const float* o       = (const float*)d_in[0];
    const float* d       = (const float*)d_in[1];
    const float* tnear   = (const float*)d_in[2];
    const float* tfar    = (const float*)d_in[3];
    const float* noise   = (const float*)d_in[4];
    const float* W1      = (const float*)d_in[5];
    const float* b1      = (const float*)d_in[6];
    const float* w_sigma = (const float*)d_in[7];
    const float* W_rgb   = (const float*)d_in[8];
    float* out = (float*)d_out;

    dim3 block(64 * CHUNKS);                       // 256
    dim3 grid(N_RAYS / RAYS_PER_BLOCK);            // 1024
    hipLaunchKernelGGL(radiance_kernel, grid, block, 0, stream,
                       o, d, tnear, tfar, noise, W1, b1, w_sigma, W_rgb, out);
}

// Round 3
// 115.359 us; speedup vs baseline: 1.0623x; 1.0395x over previous
//
#include <hip/hip_runtime.h>
#include <math.h>

#define N_RAYS 65536
#define T_SAMPLES 128
#define HID 16

#define RAYS_PER_BLOCK 64
#define CHUNKS 4
#define CHUNK_LEN (T_SAMPLES / CHUNKS)   // 32

// log2(e)
#define L2E 1.4426950408889634f

// block=256 (4 waves), min 4 waves/EU -> VGPR cap 128: enough to keep
// A[16]/B[16] live across the t-loop (at the default heuristic the compiler
// allocated 32 VGPRs and rematerialized A/B every iteration, doubling VALU).
__global__ __launch_bounds__(256, 4) void radiance_kernel(
    const float* __restrict__ o,
    const float* __restrict__ d,
    const float* __restrict__ tnear,
    const float* __restrict__ tfar,
    const float* __restrict__ noise,
    const float* __restrict__ W1,
    const float* __restrict__ b1,
    const float* __restrict__ w_sigma,
    const float* __restrict__ W_rgb,
    float* __restrict__ out)
{
    const int lane  = threadIdx.x & 63;   // ray within block (wave-coherent)
    const int chunk = threadIdx.x >> 6;   // 0..3 (one wave per chunk)
    const int ray   = blockIdx.x * RAYS_PER_BLOCK + lane;

    // ---- per-ray setup (duplicated across the 4 chunk-waves; cheap) ----
    const float ox = o[ray*3+0], oy = o[ray*3+1], oz = o[ray*3+2];
    const float dx = d[ray*3+0], dy = d[ray*3+1], dz = d[ray*3+2];
    const float tn = tnear[ray];
    const float tf = tfar[ray];
    const float dnorm = sqrtf(dx*dx + dy*dy + dz*dz);
    const float sc = (tf - tn) * (1.0f / (float)T_SAMPLES);

    // Hoisted MLP layer 1: h_j(ts) = relu(A_j + ts*B_j)
    float A[HID], B[HID];
#pragma unroll
    for (int j = 0; j < HID; ++j) {
        const float w0 = W1[0*HID + j], w1 = W1[1*HID + j], w2 = W1[2*HID + j];
        A[j] = fmaf(ox, w0, fmaf(oy, w1, fmaf(oz, w2, b1[j])));
        B[j] = fmaf(dx, w0, fmaf(dy, w1, dz * w2));
    }
    // Output weights: uniform-indexed -> SGPRs
    float WS[HID], WR[HID], WG[HID], WB[HID];
#pragma unroll
    for (int j = 0; j < HID; ++j) {
        WS[j] = w_sigma[j];
        WR[j] = W_rgb[j*3+0];
        WG[j] = W_rgb[j*3+1];
        WB[j] = W_rgb[j*3+2];
    }

    // ---- this thread's sample chunk [t0, t0+CHUNK_LEN) ----
    const int t0 = chunk * CHUNK_LEN;
    const float nz0 = noise[(size_t)t0 * N_RAYS + ray];
    float fi = (float)t0;                        // float sample counter
    float ts = fmaf(sc, fi + nz0, tn);

    float lt = 1.0f;   // local transmittance within chunk
    float cr = 0.f, cg = 0.f, cb = 0.f, cd = 0.f, ca = 0.f;

    for (int i = 0; i < CHUNK_LEN; ++i) {
        const int t = t0 + i;
        const bool has_next = (t + 1 < T_SAMPLES);   // wave-uniform
        float nz_next = 0.0f;
        if (has_next) nz_next = noise[(size_t)(t+1) * N_RAYS + ray];

        float sp = 0.f, rr = 0.f, gg = 0.f, bb = 0.f;
#pragma unroll
        for (int j = 0; j < HID; ++j) {
            const float h = fmaxf(fmaf(ts, B[j], A[j]), 0.0f);
            sp = fmaf(h, WS[j], sp);
            rr = fmaf(h, WR[j], rr);
            gg = fmaf(h, WG[j], gg);
            bb = fmaf(h, WB[j], bb);
        }

        const float ts_next = has_next ? fmaf(sc, fi + 1.0f + nz_next, tn) : tf;

        // l2 = log2(1 + exp(sp))  (stable): max(sp,0)*L2E + log2(1 + 2^(-|sp|*L2E))
        const float e  = __builtin_amdgcn_exp2f(-fabsf(sp) * L2E);
        const float l2 = fmaf(fmaxf(sp, 0.0f), L2E, __builtin_amdgcn_logf(1.0f + e));
        // exp(-sigma*delta*dnorm) = 2^(-delta*dnorm*l2)
        const float dd = (ts_next - ts) * dnorm;
        const float et = __builtin_amdgcn_exp2f(-dd * l2);

        // sigmoids via base-2
        const float r = __builtin_amdgcn_rcpf(1.0f + __builtin_amdgcn_exp2f(-rr * L2E));
        const float g = __builtin_amdgcn_rcpf(1.0f + __builtin_amdgcn_exp2f(-gg * L2E));
        const float b = __builtin_amdgcn_rcpf(1.0f + __builtin_amdgcn_exp2f(-bb * L2E));

        const float w = lt * (1.0f - et);
        cr = fmaf(w, r, cr);
        cg = fmaf(w, g, cg);
        cb = fmaf(w, b, cb);
        cd = fmaf(w, ts, cd);
        ca += w;
        lt *= et;
        ts = ts_next;
        fi += 1.0f;
    }

    // ---- combine chunks: out_c scaled by product of previous chunks' lt ----
    __shared__ float s_lt[CHUNKS][RAYS_PER_BLOCK];
    __shared__ float s_acc[CHUNKS][5][RAYS_PER_BLOCK];
    s_lt[chunk][lane] = lt;
    s_acc[chunk][0][lane] = cr;
    s_acc[chunk][1][lane] = cg;
    s_acc[chunk][2][lane] = cb;
    s_acc[chunk][3][lane] = cd;
    s_acc[chunk][4][lane] = ca;
    __syncthreads();

    if (chunk == 0) {
        float scale = 1.0f;
        float a0 = 0.f, a1 = 0.f, a2 = 0.f, a3 = 0.f, a4 = 0.f;
#pragma unroll
        for (int c = 0; c < CHUNKS; ++c) {
            a0 = fmaf(scale, s_acc[c][0][lane], a0);
            a1 = fmaf(scale, s_acc[c][1][lane], a1);
            a2 = fmaf(scale, s_acc[c][2][lane], a2);
            a3 = fmaf(scale, s_acc[c][3][lane], a3);
            a4 = fmaf(scale, s_acc[c][4][lane], a4);
            scale *= s_lt[c][lane];
        }
        out[ray*5+0] = a0;
        out[ray*5+1] = a1;
        out[ray*5+2] = a2;
        out[ray*5+3] = a3;
        out[ray*5+4] = a4;
    }
}

extern "C" void kernel_launch(void* const* d_in, const int* in_sizes, int n_in,
                              void* d_out, int out_size, void* d_ws, size_t ws_size,
                              hipStream_t stream) {
    const float* o       = (const float*)d_in[0];
    const float* d       = (const float*)d_in[1];
    const float* tnear   = (const float*)d_in[2];
    const float* tfar    = (const float*)d_in[3];
    const float* noise   = (const float*)d_in[4];
    const float* W1      = (const float*)d_in[5];
    const float* b1      = (const float*)d_in[6];
    const float* w_sigma = (const float*)d_in[7];
    const float* W_rgb   = (const float*)d_in[8];
    float* out = (float*)d_out;

    dim3 block(64 * CHUNKS);                       // 256
    dim3 grid(N_RAYS / RAYS_PER_BLOCK);            // 1024
    hipLaunchKernelGGL(radiance_kernel, grid, block, 0, stream,
                       o, d, tnear, tfar, noise, W1, b1, w_sigma, W_rgb, out);
}